// Round 4
// baseline (195.174 us; speedup 1.0000x reference)
//
#include <hip/hip_runtime.h>

#define B_  4
#define N_  4096
#define C_  256
#define D_  128
#define M_  4095
#define BN_ (B_ * N_)
#define KSPLIT 4

typedef _Float16 half_t;
typedef __attribute__((ext_vector_type(8))) _Float16 half8;
typedef __attribute__((ext_vector_type(4))) _Float16 half4;
typedef __attribute__((ext_vector_type(4))) float f32x4;

#define MFMA16x16x32(A, B, C) __builtin_amdgcn_mfma_f32_16x16x32_f16(A, B, C, 0, 0, 0)
#define LOG2E 1.44269504088896f
#define RTHR  5.0f   // defer-max threshold (base-2): p bounded by 2^5 = 32

// XOR bank swizzle (half-element index): byte ^= (row&7)<<4.
#define SWZ(r, c) ((c) ^ (((r) & 7) << 3))

// global -> LDS direct DMA, 16 B per lane. LDS dest is wave-uniform base +
// lane*16 (hardware rule); global src is per-lane (pre-swizzled there).
__device__ __forceinline__ void gld16(const void* g, void* l) {
    __builtin_amdgcn_global_load_lds(
        (const __attribute__((address_space(1))) unsigned char*)g,
        (__attribute__((address_space(3))) unsigned char*)l, 16, 0, 0);
}

// ---- prep: weights into B-fragment layouts (runs once, tiny) ----
__global__ __launch_bounds__(256) void prep_kernel(
    const float* __restrict__ Wt, const float* __restrict__ Wp,
    const float* __restrict__ Wg, const float* __restrict__ Wf,
    half_t* __restrict__ WT_hi, half_t* __restrict__ WfT)
{
    const int idx = blockIdx.x * 256 + threadIdx.x;   // 0..32767
    const int wsel = blockIdx.y;
    if (wsel < 3) {
        const float* __restrict__ W = (wsel == 0) ? Wt : (wsel == 1) ? Wp : Wg;
        const int d = idx >> 8, c = idx & 255;
        WT_hi[(size_t)wsel * 32768 + idx] = (half_t)W[(size_t)c * D_ + d];
    } else {
        const int c = idx >> 7, d = idx & 127;
        WfT[idx] = (half_t)Wf[(size_t)d * C_ + c];
    }
}

// ---- proj (single-fp16 MFMA) + FUSED maxpool/transpose ---- (unchanged)
__global__ __launch_bounds__(256) void proj_kernel(
    const float* __restrict__ x, const half_t* __restrict__ WT_hi,
    half_t* __restrict__ theta, half_t* __restrict__ pphi,
    half_t* __restrict__ pgT)
{
    const int tid = threadIdx.x;
    const int lane = tid & 63;
    const int w = tid >> 6;        // wave -> rows w*16 .. w*16+15
    const int lm = lane & 15;
    const int lq = lane >> 4;
    const int r0 = blockIdx.x * 64;
    const int which = blockIdx.y;
    const half_t* __restrict__ Wg_ = WT_hi + (size_t)which * 32768;

    __shared__ __align__(16) unsigned char lds_raw[18432];
    half_t (*Xh)[40]  = (half_t (*)[40])(lds_raw);            //  64 x 40 =  5,120 B
    half_t (*Whl)[40] = (half_t (*)[40])(lds_raw + 5120);     // 128 x 40 = 10,240 B

    f32x4 acc[8];
#pragma unroll
    for (int nb = 0; nb < 8; ++nb)
#pragma unroll
        for (int r = 0; r < 4; ++r) acc[nb][r] = 0.f;

    const int xr = tid >> 2, xc = (tid & 3) * 8;   // x stage: 64r x 32c
    const int wr = tid >> 1, wc = (tid & 1) * 16;  // W stage: 128d x 32c

    // prefetch chunk 0
    const float* xs = x + (size_t)(r0 + xr) * C_ + xc;
    const half_t* wsrc = Wg_ + (size_t)wr * 256 + wc;
    float4 xv0 = *(const float4*)&xs[0];
    float4 xv1 = *(const float4*)&xs[4];
    half8 wv0 = *(const half8*)&wsrc[0];
    half8 wv1 = *(const half8*)&wsrc[8];

    for (int kc = 0; kc < 8; ++kc) {   // C = 256 in chunks of 32
        half8 hi;
        hi[0] = (half_t)xv0.x; hi[1] = (half_t)xv0.y;
        hi[2] = (half_t)xv0.z; hi[3] = (half_t)xv0.w;
        hi[4] = (half_t)xv1.x; hi[5] = (half_t)xv1.y;
        hi[6] = (half_t)xv1.z; hi[7] = (half_t)xv1.w;
        half8 w0 = wv0, w1 = wv1;
        __syncthreads();               // previous chunk's frags consumed
        *(half8*)&Xh[xr][xc] = hi;
        *(half8*)&Whl[wr][wc]     = w0;
        *(half8*)&Whl[wr][wc + 8] = w1;
        if (kc < 7) {                  // issue next chunk's loads (hidden under MFMA)
            xs += 32; wsrc += 32;
            xv0 = *(const float4*)&xs[0];
            xv1 = *(const float4*)&xs[4];
            wv0 = *(const half8*)&wsrc[0];
            wv1 = *(const half8*)&wsrc[8];
        }
        __syncthreads();

        half8 ah = *(const half8*)&Xh[w * 16 + lm][lq * 8];
#pragma unroll
        for (int nb = 0; nb < 8; ++nb) {
            half8 bh = *(const half8*)&Whl[nb * 16 + lm][lq * 8];
            acc[nb] = MFMA16x16x32(ah, bh, acc[nb]);
        }
    }

    if (which == 0) {   // theta: scale by log2e, store fp16 (QK runs in base-2)
#pragma unroll
        for (int nb = 0; nb < 8; ++nb)
#pragma unroll
            for (int r = 0; r < 4; ++r)
                theta[(size_t)(r0 + w * 16 + lq * 4 + r) * D_ + nb * 16 + lm] =
                    (half_t)(acc[nb][r] * LOG2E);
        return;
    }

    // ---- fused pool path: acc -> LsT[d][m] fp16, halo row, pool, store ----
    __syncthreads();   // staging arrays dead
    half_t (*LsT)[72] = (half_t (*)[72])(lds_raw);   // 128 x 72 = 18,432 B
#pragma unroll
    for (int nb = 0; nb < 8; ++nb) {
        const int d = nb * 16 + lm;
        const int m = w * 16 + lq * 4;
        half4 pk;
#pragma unroll
        for (int r = 0; r < 4; ++r) pk[r] = (half_t)acc[nb][r];
        *(half4*)&LsT[d][m] = pk;
    }
    // halo: projected row r0+64 (or r0+63 at batch boundary) -> LsT[d][64]
    if (tid < 128) {
        int rh = r0 + 64;
        if ((rh & (N_ - 1)) == 0) rh = r0 + 63;
        const float* xrow = x + (size_t)rh * C_;
        const half_t* wrow = Wg_ + (size_t)tid * 256;
        float s = 0.f;
#pragma unroll
        for (int c8 = 0; c8 < 32; ++c8) {
            half8 h = *(const half8*)&wrow[c8 * 8];
            float4 xa = *(const float4*)&xrow[c8 * 8];
            float4 xb = *(const float4*)&xrow[c8 * 8 + 4];
            s += xa.x * (float)h[0] + xa.y * (float)h[1]
               + xa.z * (float)h[2] + xa.w * (float)h[3]
               + xb.x * (float)h[4] + xb.y * (float)h[5]
               + xb.z * (float)h[6] + xb.w * (float)h[7];
        }
        LsT[tid][64] = (half_t)s;
    }
    __syncthreads();

    if (which == 1) {   // pooled phi -> pphi[m][d]
        const int m = tid >> 2, dh = (tid & 3) * 32;
        half8 o[4];
#pragma unroll
        for (int j = 0; j < 32; ++j) {
            float v0 = (float)LsT[dh + j][m];
            float v1 = (float)LsT[dh + j][m + 1];
            o[j >> 3][j & 7] = (half_t)fmaxf(v0, v1);
        }
        half8* dst = (half8*)&pphi[(size_t)(r0 + m) * D_ + dh];
#pragma unroll
        for (int j = 0; j < 4; ++j) dst[j] = o[j];
    } else {            // pooled g -> pgT[b][d][m]
        const int d = tid >> 1, mh = (tid & 1) * 32;
        const int b = r0 / N_, m0 = r0 & (N_ - 1);
        half8 in[4];
#pragma unroll
        for (int j = 0; j < 4; ++j) in[j] = *(const half8*)&LsT[d][mh + j * 8];
        const half_t ext = LsT[d][mh + 32];
        half8 o[4];
#pragma unroll
        for (int j = 0; j < 32; ++j) {
            float v0 = (float)in[j >> 3][j & 7];
            float v1 = (j == 31) ? (float)ext : (float)in[(j + 1) >> 3][(j + 1) & 7];
            o[j >> 3][j & 7] = (half_t)fmaxf(v0, v1);
        }
        half8* dst = (half8*)&pgT[((size_t)b * D_ + d) * N_ + m0 + mh];
#pragma unroll
        for (int j = 0; j < 4; ++j) dst[j] = o[j];
    }
}

// ---------------- MFMA flash attention, transposed scores, base-2 ----------
// r13: double-buffered K/G staged via global_load_lds DMA (zero register
// residency -> no r10-style spill; HBM latency hides under compute). LDS is
// LINEAR (DMA requirement); swizzle applied to the GLOBAL source addresses
// and matched on reads (both-sides rule). LDS = 80 KB -> exactly 2 blocks/CU
// (the L2-friendly residency; 3/CU regressed in r12 via +9.6 MB HBM traffic).
// KSPLIT back to 4: 512 blocks all co-resident, ypart traffic halved.
template<int KS>
__global__ __launch_bounds__(256) void attn_kernel(
    const half_t* __restrict__ theta, const half_t* __restrict__ pphi,
    const half_t* __restrict__ pgT, half_t* __restrict__ ypart,
    float* __restrict__ mstat, float* __restrict__ lstat)
{
    const int TILES = 64 / KS;     // key-tiles of 64 keys
    const int tid = threadIdx.x;
    const int lane = tid & 63;
    const int w = tid >> 6;
    const int lm = lane & 15;
    const int lq = lane >> 4;      // 0..3
    const int qt = blockIdx.x, ksb = blockIdx.y, b = blockIdx.z;
    const int q0 = qt * 128;
    const int kt0 = ksb * TILES, kt1 = kt0 + TILES;

    __shared__ half_t Ks[2][64][128];   // K tiles [key][d]   2 x 16,384 B
    __shared__ half_t Gts[2][128][64];  // G tiles [d][key]   2 x 16,384 B
    __shared__ half_t Ps[128][64];      // P [q][key] wave-private 16,384 B

    // Q B-frags (B[k=d][n=q]): direct fp16 loads (theta already *log2e)
    half8 qh[2][4];
#pragma unroll
    for (int nb = 0; nb < 2; ++nb) {
        const half_t* tr_ = theta + ((size_t)b * N_ + q0 + w * 32 + nb * 16 + lm) * D_;
#pragma unroll
        for (int k4 = 0; k4 < 4; ++k4)
            qh[nb][k4] = *(const half8*)(tr_ + k4 * 32 + lq * 8);
    }

    // ---- DMA staging: per-lane pre-swizzled global sources ----
    // K tile kt is 16,384 contiguous bytes at kbase + kt*16384 (rows=keys).
    // G row d is at gbase + d*8192 + kt*128 (64 keys * 2 B per tile).
    const char* kbase = (const char*)(pphi + (size_t)b * N_ * D_);
    const char* gbase = (const char*)(pgT + (size_t)b * D_ * N_);
    const int rlo4 = lane >> 4;                          // K row-within-4
    const int kco  = (lane & 15) * 16;                   // K chunk byte (pre-swz)
    const int rlo8 = lane >> 3;                          // G row-within-8 (= d&7)
    const int gco  = ((lane & 7) * 16) ^ (rlo8 << 4);    // G swizzled chunk byte

    auto stage = [&](int bf, int kt) {
#pragma unroll
        for (int i = 0; i < 4; ++i) {
            const int r4 = w * 4 + i;
            const int krow = r4 * 4 + rlo4;
            gld16(kbase + (size_t)kt * 16384 + (size_t)krow * 256
                        + (kco ^ ((krow & 7) << 4)),
                  &Ks[bf][r4 * 4][0]);
            const int gd = r4 * 8 + rlo8;
            gld16(gbase + (size_t)gd * (N_ * 2) + (size_t)kt * 128 + gco,
                  &Gts[bf][r4 * 8][0]);
        }
    };

    float m_i[2] = {-1e30f, -1e30f};
    float l_i[2] = {0.f, 0.f};      // per-quad partial; cross-quad sum deferred
    f32x4 yacc[2][8];
#pragma unroll
    for (int mb = 0; mb < 2; ++mb)
#pragma unroll
        for (int dn = 0; dn < 8; ++dn)
#pragma unroll
            for (int r = 0; r < 4; ++r) yacc[mb][dn][r] = 0.f;

    int cur = 0;
    stage(0, kt0);
    __syncthreads();   // emits vmcnt(0) drain -> tile kt0 resident

    for (int kt = kt0; kt < kt1; ++kt) {
        const int k0 = kt * 64;
        const bool has_next = (kt + 1 < kt1);
        // issue next tile's DMA now; it completes during compute below.
        // Safe: buf[cur^1] was last read in iter kt-1, whose trailing barrier
        // all waves have passed.
        if (has_next) stage(cur ^ 1, kt + 1);

        // QK^T transposed: S^T[key][q]; A = K (LDS, swizzled read), B = Q (regs)
        f32x4 sc[4][2];
#pragma unroll
        for (int kb = 0; kb < 4; ++kb)
#pragma unroll
            for (int nb = 0; nb < 2; ++nb)
#pragma unroll
                for (int r = 0; r < 4; ++r) sc[kb][nb][r] = 0.f;
        __builtin_amdgcn_s_setprio(1);
#pragma unroll
        for (int kb = 0; kb < 4; ++kb) {
            const int krow = kb * 16 + lm;
#pragma unroll
            for (int k4 = 0; k4 < 4; ++k4) {
                half8 kf = *(const half8*)&Ks[cur][krow][SWZ(krow, k4 * 32 + lq * 8)];
#pragma unroll
                for (int nb = 0; nb < 2; ++nb)
                    sc[kb][nb] = MFMA16x16x32(kf, qh[nb][k4], sc[kb][nb]);
            }
        }
        __builtin_amdgcn_s_setprio(0);
        // mask padded key 4095 (only last tile of last split)
        if (k0 + 64 > M_) {
#pragma unroll
            for (int kb = 0; kb < 4; ++kb)
#pragma unroll
                for (int r = 0; r < 4; ++r)
                    if (k0 + kb * 16 + lq * 4 + r >= M_) {
                        sc[kb][0][r] = -1e30f; sc[kb][1][r] = -1e30f;
                    }
        }

        // ---- online softmax (base-2) with defer-max ----
        float mt[2];
#pragma unroll
        for (int nb = 0; nb < 2; ++nb) {
            float m0 = -1e30f;
#pragma unroll
            for (int kb = 0; kb < 4; ++kb)
#pragma unroll
                for (int r = 0; r < 4; ++r) m0 = fmaxf(m0, sc[kb][nb][r]);
            m0 = fmaxf(m0, __shfl_xor(m0, 16, 64));
            m0 = fmaxf(m0, __shfl_xor(m0, 32, 64));
            mt[nb] = m0;   // uniform across quads, per q-col lm
        }
        const bool need0 = __any(mt[0] > m_i[0] + RTHR);
        const bool need1 = __any(mt[1] > m_i[1] + RTHR);
        float alphav[2] = {1.f, 1.f};
#pragma unroll
        for (int nb = 0; nb < 2; ++nb) {
            const bool need = nb ? need1 : need0;
            float mnew = m_i[nb];
            if (need) {   // wave-uniform (rare after first tiles)
                mnew = fmaxf(m_i[nb], mt[nb]);
                alphav[nb] = exp2f(m_i[nb] - mnew);
                m_i[nb] = mnew;
            }
            float rs = 0.f;
            const int prow = w * 32 + nb * 16 + lm;
#pragma unroll
            for (int kb = 0; kb < 4; ++kb) {
                half4 pk;
#pragma unroll
                for (int r = 0; r < 4; ++r) {
                    float p = exp2f(sc[kb][nb][r] - mnew);   // p <= 2^RTHR
                    rs += p;
                    pk[r] = (half_t)p;
                }
                *(half4*)&Ps[prow][SWZ(prow, kb * 16 + lq * 4)] = pk;
            }
            l_i[nb] = l_i[nb] * alphav[nb] + rs;
        }
        // rescale accumulator only on rescue tiles (wave-uniform branches)
        if (need0) {
            float a_t[4];
#pragma unroll
            for (int r = 0; r < 4; ++r) a_t[r] = __shfl(alphav[0], lq * 4 + r, 16);
#pragma unroll
            for (int dn = 0; dn < 8; ++dn)
#pragma unroll
                for (int r = 0; r < 4; ++r) yacc[0][dn][r] *= a_t[r];
        }
        if (need1) {
            float a_t[4];
#pragma unroll
            for (int r = 0; r < 4; ++r) a_t[r] = __shfl(alphav[1], lq * 4 + r, 16);
#pragma unroll
            for (int dn = 0; dn < 8; ++dn)
#pragma unroll
                for (int r = 0; r < 4; ++r) yacc[1][dn][r] *= a_t[r];
        }

        // PV: A = P (LDS, wave-private -> no barrier), B = G^T (LDS)
        half8 pf[2][2];
#pragma unroll
        for (int mb = 0; mb < 2; ++mb) {
            const int prow = w * 32 + mb * 16 + lm;
#pragma unroll
            for (int k2 = 0; k2 < 2; ++k2)
                pf[mb][k2] = *(const half8*)&Ps[prow][SWZ(prow, k2 * 32 + lq * 8)];
        }
        __builtin_amdgcn_s_setprio(1);
#pragma unroll
        for (int dn = 0; dn < 8; ++dn) {
            const int grow = dn * 16 + lm;
#pragma unroll
            for (int k2 = 0; k2 < 2; ++k2) {
                half8 gf = *(const half8*)&Gts[cur][grow][SWZ(grow, k2 * 32 + lq * 8)];
                yacc[0][dn] = MFMA16x16x32(pf[0][k2], gf, yacc[0][dn]);
                yacc[1][dn] = MFMA16x16x32(pf[1][k2], gf, yacc[1][dn]);
            }
        }
        __builtin_amdgcn_s_setprio(0);

        if (has_next) {
            __syncthreads();   // vmcnt(0)+barrier: next tile's DMA resident
            cur ^= 1;
        }
    }

    // epilogue: finish l (cross-quad sum, deferred from the k-loop)
#pragma unroll
    for (int nb = 0; nb < 2; ++nb) {
        l_i[nb] += __shfl_xor(l_i[nb], 16, 64);
        l_i[nb] += __shfl_xor(l_i[nb], 32, 64);
    }
    // unnormalized y partial (fp16) + (m,l) stats (m in base-2)
    half_t* yp = ypart + ((size_t)ksb * BN_ + (size_t)b * N_) * D_;
#pragma unroll
    for (int mb = 0; mb < 2; ++mb)
#pragma unroll
        for (int dn = 0; dn < 8; ++dn)
#pragma unroll
            for (int r = 0; r < 4; ++r)
                yp[(size_t)(q0 + w * 32 + mb * 16 + lq * 4 + r) * D_ + dn * 16 + lm] =
                    (half_t)yacc[mb][dn][r];
    if (lq == 0) {
#pragma unroll
        for (int nb = 0; nb < 2; ++nb) {
            const int row = q0 + w * 32 + nb * 16 + lm;
            mstat[(size_t)ksb * BN_ + (size_t)b * N_ + row] = m_i[nb];
            lstat[(size_t)ksb * BN_ + (size_t)b * N_ + row] = l_i[nb];
        }
    }
}

// ---- final (MFMA): merge KS partials (base-2 stats), z = x + y @ Wf ----
// 64x128 tiles, grid (BN/64, 2): merge redundancy x2. Swizzled linear LDS.
template<int KS>
__global__ __launch_bounds__(256) void final_kernel(
    const half_t* __restrict__ ypart, const float* __restrict__ mstat,
    const float* __restrict__ lstat, const float* __restrict__ x,
    const half_t* __restrict__ WfT, float* __restrict__ out)
{
    const int tid = threadIdx.x;
    const int lane = tid & 63;
    const int w = tid >> 6;
    const int lm = lane & 15;
    const int lq = lane >> 4;
    const int r0 = blockIdx.x * 64;
    const int c0 = blockIdx.y * 128;

    __shared__ half_t Ys[64][128];     // merged y [row][d], swizzled  16,384 B
    __shared__ half_t Wfs[128][128];   // Wf^T    [col][d], swizzled  32,768 B
    __shared__ float scl[KS][64];

    if (tid < 64) {
        const int row = r0 + tid;
        float mv[KS], lv[KS], wv[KS];
        float Mx = -1e30f;
#pragma unroll
        for (int s = 0; s < KS; ++s) {
            mv[s] = mstat[(size_t)s * BN_ + row];
            lv[s] = lstat[(size_t)s * BN_ + row];
            Mx = fmaxf(Mx, mv[s]);
        }
        float lsum = 0.f;
#pragma unroll
        for (int s = 0; s < KS; ++s) { wv[s] = exp2f(mv[s] - Mx); lsum += wv[s] * lv[s]; }
        const float inv = 1.f / lsum;
#pragma unroll
        for (int s = 0; s < KS; ++s) scl[s][tid] = wv[s] * inv;
    }
    // stage Wfs: 128 cols x 128 d (no dependence on scl)
    {
        const int wc = tid >> 1, wd = (tid & 1) * 64;
        const half_t* wf = WfT + (size_t)(c0 + wc) * D_ + wd;
#pragma unroll
        for (int q = 0; q < 8; ++q)
            *(half8*)&Wfs[wc][SWZ(wc, wd + q * 8)] = *(const half8*)&wf[q * 8];
    }
    __syncthreads();

    // merge + stage Ys: thread covers row sr, d-range [dd, dd+32)
    {
        const int sr = tid >> 2;
        const int dd = (tid & 3) * 32;
        float ss[KS];
#pragma unroll
        for (int s = 0; s < KS; ++s) ss[s] = scl[s][sr];
        const size_t yb = (size_t)(r0 + sr) * D_ + dd;
        half8 o[4];
#pragma unroll
        for (int q = 0; q < 4; ++q) {
            float m[8];
#pragma unroll
            for (int j = 0; j < 8; ++j) m[j] = 0.f;
#pragma unroll
            for (int s = 0; s < KS; ++s) {
                half8 yv = *(const half8*)&ypart[(size_t)s * BN_ * D_ + yb + q * 8];
#pragma unroll
                for (int j = 0; j < 8; ++j) m[j] += ss[s] * (float)yv[j];
            }
#pragma unroll
            for (int j = 0; j < 8; ++j) o[q][j] = (half_t)m[j];
        }
#pragma unroll
        for (int q = 0; q < 4; ++q) *(half8*)&Ys[sr][SWZ(sr, dd + q * 8)] = o[q];
    }
    __syncthreads();

    f32x4 acc[8];
#pragma unroll
    for (int nb = 0; nb < 8; ++nb)
#pragma unroll
        for (int r = 0; r < 4; ++r) acc[nb][r] = 0.f;

    const int yrow = w * 16 + lm;
#pragma unroll
    for (int k4 = 0; k4 < 4; ++k4) {
        half8 af = *(const half8*)&Ys[yrow][SWZ(yrow, k4 * 32 + lq * 8)];
#pragma unroll
        for (int nb = 0; nb < 8; ++nb) {
            const int wrow = nb * 16 + lm;
            half8 bf = *(const half8*)&Wfs[wrow][SWZ(wrow, k4 * 32 + lq * 8)];
            acc[nb] = MFMA16x16x32(af, bf, acc[nb]);
        }
    }

#pragma unroll
    for (int nb = 0; nb < 8; ++nb)
#pragma unroll
        for (int r = 0; r < 4; ++r) {
            const int row = r0 + w * 16 + lq * 4 + r;
            const int col = c0 + nb * 16 + lm;
            out[(size_t)row * C_ + col] =
                acc[nb][r] + x[(size_t)row * C_ + col];
        }
}

extern "C" void kernel_launch(void* const* d_in, const int* in_sizes, int n_in,
                              void* d_out, int out_size, void* d_ws, size_t ws_size,
                              hipStream_t stream)
{
    const float* x  = (const float*)d_in[0];
    const float* Wt = (const float*)d_in[1];
    const float* Wp = (const float*)d_in[2];
    const float* Wg = (const float*)d_in[3];
    const float* Wf = (const float*)d_in[4];
    float* out = (float*)d_out;

    const size_t SEG = (size_t)BN_ * D_;   // elements (2,097,152)

    half_t* hb    = (half_t*)d_ws;
    half_t* theta = hb;
    half_t* pphi  = hb + SEG;
    half_t* pgT   = hb + 2 * SEG;
    half_t* ypart = hb + 3 * SEG;
    float*  mstat = (float*)(hb + (size_t)(3 + KSPLIT) * SEG);
    float*  lstat = mstat + (size_t)KSPLIT * BN_;
    half_t* WT_hi = (half_t*)(lstat + (size_t)KSPLIT * BN_);
    half_t* WfT   = WT_hi + 3 * 32768;

    prep_kernel<<<dim3(128, 4), 256, 0, stream>>>(Wt, Wp, Wg, Wf, WT_hi, WfT);
    proj_kernel<<<dim3(BN_ / 64, 3), 256, 0, stream>>>(x, WT_hi, theta, pphi, pgT);
    attn_kernel<KSPLIT><<<dim3(N_ / 128, KSPLIT, B_), 256, 0, stream>>>(
        theta, pphi, pgT, ypart, mstat, lstat);
    final_kernel<KSPLIT><<<dim3(BN_ / 64, 2), 256, 0, stream>>>(
        ypart, mstat, lstat, x, WfT, out);
}

// Round 5
// 174.952 us; speedup vs baseline: 1.1156x; 1.1156x over previous
//
#include <hip/hip_runtime.h>

#define B_  4
#define N_  4096
#define C_  256
#define D_  128
#define M_  4095
#define BN_ (B_ * N_)

typedef _Float16 half_t;
typedef __attribute__((ext_vector_type(8))) _Float16 half8;
typedef __attribute__((ext_vector_type(4))) _Float16 half4;
typedef __attribute__((ext_vector_type(4))) float f32x4;

#define MFMA16x16x32(A, B, C) __builtin_amdgcn_mfma_f32_16x16x32_f16(A, B, C, 0, 0, 0)
#define LOG2E 1.44269504088896f
#define RTHR  5.0f   // defer-max threshold (base-2): p bounded by 2^5 = 32

// XOR bank swizzle (half-element index) for the final GEMM's linear tiles.
#define SWZ(r, c) ((c) ^ (((r) & 7) << 3))

// ---- prep: weights into B-fragment layouts (runs once, tiny) ----
__global__ __launch_bounds__(256) void prep_kernel(
    const float* __restrict__ Wt, const float* __restrict__ Wp,
    const float* __restrict__ Wg, const float* __restrict__ Wf,
    half_t* __restrict__ WT_hi, half_t* __restrict__ WfT)
{
    const int idx = blockIdx.x * 256 + threadIdx.x;   // 0..32767
    const int wsel = blockIdx.y;
    if (wsel < 3) {
        const float* __restrict__ W = (wsel == 0) ? Wt : (wsel == 1) ? Wp : Wg;
        const int d = idx >> 8, c = idx & 255;
        WT_hi[(size_t)wsel * 32768 + idx] = (half_t)W[(size_t)c * D_ + d];
    } else {
        const int c = idx >> 7, d = idx & 127;
        WfT[idx] = (half_t)Wf[(size_t)d * C_ + c];
    }
}

// ---- proj (single-fp16 MFMA) + FUSED maxpool/transpose ---- (unchanged)
__global__ __launch_bounds__(256) void proj_kernel(
    const float* __restrict__ x, const half_t* __restrict__ WT_hi,
    half_t* __restrict__ theta, half_t* __restrict__ pphi,
    half_t* __restrict__ pgT)
{
    const int tid = threadIdx.x;
    const int lane = tid & 63;
    const int w = tid >> 6;        // wave -> rows w*16 .. w*16+15
    const int lm = lane & 15;
    const int lq = lane >> 4;
    const int r0 = blockIdx.x * 64;
    const int which = blockIdx.y;
    const half_t* __restrict__ Wg_ = WT_hi + (size_t)which * 32768;

    __shared__ __align__(16) unsigned char lds_raw[18432];
    half_t (*Xh)[40]  = (half_t (*)[40])(lds_raw);            //  64 x 40 =  5,120 B
    half_t (*Whl)[40] = (half_t (*)[40])(lds_raw + 5120);     // 128 x 40 = 10,240 B

    f32x4 acc[8];
#pragma unroll
    for (int nb = 0; nb < 8; ++nb)
#pragma unroll
        for (int r = 0; r < 4; ++r) acc[nb][r] = 0.f;

    const int xr = tid >> 2, xc = (tid & 3) * 8;   // x stage: 64r x 32c
    const int wr = tid >> 1, wc = (tid & 1) * 16;  // W stage: 128d x 32c

    // prefetch chunk 0
    const float* xs = x + (size_t)(r0 + xr) * C_ + xc;
    const half_t* wsrc = Wg_ + (size_t)wr * 256 + wc;
    float4 xv0 = *(const float4*)&xs[0];
    float4 xv1 = *(const float4*)&xs[4];
    half8 wv0 = *(const half8*)&wsrc[0];
    half8 wv1 = *(const half8*)&wsrc[8];

    for (int kc = 0; kc < 8; ++kc) {   // C = 256 in chunks of 32
        half8 hi;
        hi[0] = (half_t)xv0.x; hi[1] = (half_t)xv0.y;
        hi[2] = (half_t)xv0.z; hi[3] = (half_t)xv0.w;
        hi[4] = (half_t)xv1.x; hi[5] = (half_t)xv1.y;
        hi[6] = (half_t)xv1.z; hi[7] = (half_t)xv1.w;
        half8 w0 = wv0, w1 = wv1;
        __syncthreads();               // previous chunk's frags consumed
        *(half8*)&Xh[xr][xc] = hi;
        *(half8*)&Whl[wr][wc]     = w0;
        *(half8*)&Whl[wr][wc + 8] = w1;
        if (kc < 7) {                  // issue next chunk's loads (hidden under MFMA)
            xs += 32; wsrc += 32;
            xv0 = *(const float4*)&xs[0];
            xv1 = *(const float4*)&xs[4];
            wv0 = *(const half8*)&wsrc[0];
            wv1 = *(const half8*)&wsrc[8];
        }
        __syncthreads();

        half8 ah = *(const half8*)&Xh[w * 16 + lm][lq * 8];
#pragma unroll
        for (int nb = 0; nb < 8; ++nb) {
            half8 bh = *(const half8*)&Whl[nb * 16 + lm][lq * 8];
            acc[nb] = MFMA16x16x32(ah, bh, acc[nb]);
        }
    }

    if (which == 0) {   // theta: scale by log2e, store fp16 (QK runs in base-2)
#pragma unroll
        for (int nb = 0; nb < 8; ++nb)
#pragma unroll
            for (int r = 0; r < 4; ++r)
                theta[(size_t)(r0 + w * 16 + lq * 4 + r) * D_ + nb * 16 + lm] =
                    (half_t)(acc[nb][r] * LOG2E);
        return;
    }

    // ---- fused pool path: acc -> LsT[d][m] fp16, halo row, pool, store ----
    __syncthreads();   // staging arrays dead
    half_t (*LsT)[72] = (half_t (*)[72])(lds_raw);   // 128 x 72 = 18,432 B
#pragma unroll
    for (int nb = 0; nb < 8; ++nb) {
        const int d = nb * 16 + lm;
        const int m = w * 16 + lq * 4;
        half4 pk;
#pragma unroll
        for (int r = 0; r < 4; ++r) pk[r] = (half_t)acc[nb][r];
        *(half4*)&LsT[d][m] = pk;
    }
    // halo: projected row r0+64 (or r0+63 at batch boundary) -> LsT[d][64]
    if (tid < 128) {
        int rh = r0 + 64;
        if ((rh & (N_ - 1)) == 0) rh = r0 + 63;
        const float* xrow = x + (size_t)rh * C_;
        const half_t* wrow = Wg_ + (size_t)tid * 256;
        float s = 0.f;
#pragma unroll
        for (int c8 = 0; c8 < 32; ++c8) {
            half8 h = *(const half8*)&wrow[c8 * 8];
            float4 xa = *(const float4*)&xrow[c8 * 8];
            float4 xb = *(const float4*)&xrow[c8 * 8 + 4];
            s += xa.x * (float)h[0] + xa.y * (float)h[1]
               + xa.z * (float)h[2] + xa.w * (float)h[3]
               + xb.x * (float)h[4] + xb.y * (float)h[5]
               + xb.z * (float)h[6] + xb.w * (float)h[7];
        }
        LsT[tid][64] = (half_t)s;
    }
    __syncthreads();

    if (which == 1) {   // pooled phi -> pphi[m][d]
        const int m = tid >> 2, dh = (tid & 3) * 32;
        half8 o[4];
#pragma unroll
        for (int j = 0; j < 32; ++j) {
            float v0 = (float)LsT[dh + j][m];
            float v1 = (float)LsT[dh + j][m + 1];
            o[j >> 3][j & 7] = (half_t)fmaxf(v0, v1);
        }
        half8* dst = (half8*)&pphi[(size_t)(r0 + m) * D_ + dh];
#pragma unroll
        for (int j = 0; j < 4; ++j) dst[j] = o[j];
    } else {            // pooled g -> pgT[b][d][m]
        const int d = tid >> 1, mh = (tid & 1) * 32;
        const int b = r0 / N_, m0 = r0 & (N_ - 1);
        half8 in[4];
#pragma unroll
        for (int j = 0; j < 4; ++j) in[j] = *(const half8*)&LsT[d][mh + j * 8];
        const half_t ext = LsT[d][mh + 32];
        half8 o[4];
#pragma unroll
        for (int j = 0; j < 32; ++j) {
            float v0 = (float)in[j >> 3][j & 7];
            float v1 = (j == 31) ? (float)ext : (float)in[(j + 1) >> 3][(j + 1) & 7];
            o[j >> 3][j & 7] = (half_t)fmaxf(v0, v1);
        }
        half8* dst = (half8*)&pgT[((size_t)b * D_ + d) * N_ + m0 + mh];
#pragma unroll
        for (int j = 0; j < 4; ++j) dst[j] = o[j];
    }
}

// ---------------- MFMA flash attention, transposed scores, base-2 ----------
// r14: byte-for-byte restore of the r2/round-2 kernel (best measured: 67.4 us
// @KS=8). Padded LDS (54,272 B, 2 blocks/CU — the L2-friendly residency),
// reg-staged loads between barriers, defer-max softmax, setprio on MFMA.
// DMA double-buffer (r13) is occupancy-infeasible: 80 KiB LDS -> 1 block/CU.
template<int KS>
__global__ __launch_bounds__(256, 2) void attn_kernel(
    const half_t* __restrict__ theta, const half_t* __restrict__ pphi,
    const half_t* __restrict__ pgT, half_t* __restrict__ ypart,
    float* __restrict__ mstat, float* __restrict__ lstat)
{
    const int TILES = 64 / KS;     // 64 key-tiles of 64 keys total
    const int tid = threadIdx.x;
    const int lane = tid & 63;
    const int w = tid >> 6;
    const int lm = lane & 15;
    const int lq = lane >> 4;      // 0..3
    const int qt = blockIdx.x, ksb = blockIdx.y, b = blockIdx.z;
    const int q0 = qt * 128;
    const int kt0 = ksb * TILES, kt1 = kt0 + TILES;

    __shared__ half_t Ks[64][136];   // K tile [key][d]        17,408 B
    __shared__ half_t Gts[128][72];  // G tile [d][key]        18,432 B
    __shared__ half_t Ps[128][72];   // P [q][key] wave-private 18,432 B

    // Q B-frags (B[k=d][n=q]): direct fp16 loads (theta already *log2e)
    half8 qh[2][4];
#pragma unroll
    for (int nb = 0; nb < 2; ++nb) {
        const half_t* tr_ = theta + ((size_t)b * N_ + q0 + w * 32 + nb * 16 + lm) * D_;
#pragma unroll
        for (int k4 = 0; k4 < 4; ++k4)
            qh[nb][k4] = *(const half8*)(tr_ + k4 * 32 + lq * 8);
    }

    // hoisted staging addresses (constant per-tile increments)
    const int key = tid >> 2, ch = tid & 3;     // K stage: 64 keys x 128 d
    const int gdd = tid >> 1, gkh = tid & 1;    // G stage: 128 d x 64 keys
    const float4* ksrc = (const float4*)(pphi +
        ((size_t)b * N_ + kt0 * 64 + key) * D_ + ch * 32);
    const float4* gsrc = (const float4*)(pgT +
        ((size_t)b * D_ + gdd) * N_ + kt0 * 64 + gkh * 32);

    float m_i[2] = {-1e30f, -1e30f};
    float l_i[2] = {0.f, 0.f};      // per-quad partial; cross-quad sum deferred
    f32x4 yacc[2][8];
#pragma unroll
    for (int mb = 0; mb < 2; ++mb)
#pragma unroll
        for (int dn = 0; dn < 8; ++dn)
#pragma unroll
            for (int r = 0; r < 4; ++r) yacc[mb][dn][r] = 0.f;

    for (int kt = kt0; kt < kt1; ++kt) {
        const int k0 = kt * 64;
        __syncthreads();
        {   // stage K [key][d] and G^T [d][key] (loads held only briefly)
            float4 a0 = ksrc[0], a1 = ksrc[1], a2 = ksrc[2], a3 = ksrc[3];
            float4 g0 = gsrc[0], g1 = gsrc[1], g2 = gsrc[2], g3 = gsrc[3];
            ksrc += 1024;   // 64 rows * 128 halfs
            gsrc += 8;      // 64 halfs
            float4* kdst = (float4*)&Ks[key][ch * 32];
            kdst[0] = a0; kdst[1] = a1; kdst[2] = a2; kdst[3] = a3;
            float4* gdst = (float4*)&Gts[gdd][gkh * 32];
            gdst[0] = g0; gdst[1] = g1; gdst[2] = g2; gdst[3] = g3;
        }
        __syncthreads();

        // QK^T transposed: S^T[key][q]; A = K (LDS), B = Q (regs)
        f32x4 sc[4][2];
#pragma unroll
        for (int kb = 0; kb < 4; ++kb)
#pragma unroll
            for (int nb = 0; nb < 2; ++nb)
#pragma unroll
                for (int r = 0; r < 4; ++r) sc[kb][nb][r] = 0.f;
        __builtin_amdgcn_s_setprio(1);
#pragma unroll
        for (int kb = 0; kb < 4; ++kb) {
#pragma unroll
            for (int k4 = 0; k4 < 4; ++k4) {
                half8 kf = *(const half8*)&Ks[kb * 16 + lm][k4 * 32 + lq * 8];
#pragma unroll
                for (int nb = 0; nb < 2; ++nb)
                    sc[kb][nb] = MFMA16x16x32(kf, qh[nb][k4], sc[kb][nb]);
            }
        }
        __builtin_amdgcn_s_setprio(0);
        // mask padded key 4095 (only last tile of last split)
        if (k0 + 64 > M_) {
#pragma unroll
            for (int kb = 0; kb < 4; ++kb)
#pragma unroll
                for (int r = 0; r < 4; ++r)
                    if (k0 + kb * 16 + lq * 4 + r >= M_) {
                        sc[kb][0][r] = -1e30f; sc[kb][1][r] = -1e30f;
                    }
        }

        // ---- online softmax (base-2) with defer-max ----
        float mt[2];
#pragma unroll
        for (int nb = 0; nb < 2; ++nb) {
            float m0 = -1e30f;
#pragma unroll
            for (int kb = 0; kb < 4; ++kb)
#pragma unroll
                for (int r = 0; r < 4; ++r) m0 = fmaxf(m0, sc[kb][nb][r]);
            m0 = fmaxf(m0, __shfl_xor(m0, 16, 64));
            m0 = fmaxf(m0, __shfl_xor(m0, 32, 64));
            mt[nb] = m0;   // uniform across quads, per q-col lm
        }
        const bool need0 = __any(mt[0] > m_i[0] + RTHR);
        const bool need1 = __any(mt[1] > m_i[1] + RTHR);
        float alphav[2] = {1.f, 1.f};
#pragma unroll
        for (int nb = 0; nb < 2; ++nb) {
            const bool need = nb ? need1 : need0;
            float mnew = m_i[nb];
            if (need) {   // wave-uniform (rare after first tiles)
                mnew = fmaxf(m_i[nb], mt[nb]);
                alphav[nb] = exp2f(m_i[nb] - mnew);
                m_i[nb] = mnew;
            }
            float rs = 0.f;
#pragma unroll
            for (int kb = 0; kb < 4; ++kb) {
                half4 pk;
#pragma unroll
                for (int r = 0; r < 4; ++r) {
                    float p = exp2f(sc[kb][nb][r] - mnew);   // p <= 2^RTHR
                    rs += p;
                    pk[r] = (half_t)p;
                }
                *(half4*)&Ps[w * 32 + nb * 16 + lm][kb * 16 + lq * 4] = pk;
            }
            l_i[nb] = l_i[nb] * alphav[nb] + rs;
        }
        // rescale accumulator only on rescue tiles (wave-uniform branches)
        if (need0) {
            float a_t[4];
#pragma unroll
            for (int r = 0; r < 4; ++r) a_t[r] = __shfl(alphav[0], lq * 4 + r, 16);
#pragma unroll
            for (int dn = 0; dn < 8; ++dn)
#pragma unroll
                for (int r = 0; r < 4; ++r) yacc[0][dn][r] *= a_t[r];
        }
        if (need1) {
            float a_t[4];
#pragma unroll
            for (int r = 0; r < 4; ++r) a_t[r] = __shfl(alphav[1], lq * 4 + r, 16);
#pragma unroll
            for (int dn = 0; dn < 8; ++dn)
#pragma unroll
                for (int r = 0; r < 4; ++r) yacc[1][dn][r] *= a_t[r];
        }

        // PV: A = P (LDS, wave-private -> no barrier), B = G^T (LDS)
        half8 pf[2][2];
#pragma unroll
        for (int mb = 0; mb < 2; ++mb)
#pragma unroll
            for (int k2 = 0; k2 < 2; ++k2)
                pf[mb][k2] = *(const half8*)&Ps[w * 32 + mb * 16 + lm][k2 * 32 + lq * 8];
        __builtin_amdgcn_s_setprio(1);
#pragma unroll
        for (int dn = 0; dn < 8; ++dn) {
#pragma unroll
            for (int k2 = 0; k2 < 2; ++k2) {
                half8 gf = *(const half8*)&Gts[dn * 16 + lm][k2 * 32 + lq * 8];
                yacc[0][dn] = MFMA16x16x32(pf[0][k2], gf, yacc[0][dn]);
                yacc[1][dn] = MFMA16x16x32(pf[1][k2], gf, yacc[1][dn]);
            }
        }
        __builtin_amdgcn_s_setprio(0);
    }

    // epilogue: finish l (cross-quad sum, deferred from the k-loop)
#pragma unroll
    for (int nb = 0; nb < 2; ++nb) {
        l_i[nb] += __shfl_xor(l_i[nb], 16, 64);
        l_i[nb] += __shfl_xor(l_i[nb], 32, 64);
    }
    // unnormalized y partial (fp16) + (m,l) stats (m in base-2)
    half_t* yp = ypart + ((size_t)ksb * BN_ + (size_t)b * N_) * D_;
#pragma unroll
    for (int mb = 0; mb < 2; ++mb)
#pragma unroll
        for (int dn = 0; dn < 8; ++dn)
#pragma unroll
            for (int r = 0; r < 4; ++r)
                yp[(size_t)(q0 + w * 32 + mb * 16 + lq * 4 + r) * D_ + dn * 16 + lm] =
                    (half_t)yacc[mb][dn][r];
    if (lq == 0) {
#pragma unroll
        for (int nb = 0; nb < 2; ++nb) {
            const int row = q0 + w * 32 + nb * 16 + lm;
            mstat[(size_t)ksb * BN_ + (size_t)b * N_ + row] = m_i[nb];
            lstat[(size_t)ksb * BN_ + (size_t)b * N_ + row] = l_i[nb];
        }
    }
}

// ---- merge: KS ypart partials -> ymerged (fp16), once per row ----
// r14 NEW: pulls the KSPLIT merge out of final_kernel so ypart (33.5 MB
// @KS=8) is read ONCE instead of once per column tile (67 MB), and the
// merge VALU runs x1. Pure streaming: 256 blocks x 256 thr.
template<int KS>
__global__ __launch_bounds__(256) void merge_kernel(
    const half_t* __restrict__ ypart, const float* __restrict__ mstat,
    const float* __restrict__ lstat, half_t* __restrict__ ymerged)
{
    const int idx = blockIdx.x * 256 + threadIdx.x;   // 0 .. BN_*4-1
    const int row = idx >> 2;
    const int dd = (idx & 3) * 32;

    float mv[KS], lv[KS], wv[KS];
    float Mx = -1e30f;
#pragma unroll
    for (int s = 0; s < KS; ++s) {
        mv[s] = mstat[(size_t)s * BN_ + row];
        lv[s] = lstat[(size_t)s * BN_ + row];
        Mx = fmaxf(Mx, mv[s]);
    }
    float lsum = 0.f;
#pragma unroll
    for (int s = 0; s < KS; ++s) { wv[s] = exp2f(mv[s] - Mx); lsum += wv[s] * lv[s]; }
    const float inv = 1.f / lsum;
#pragma unroll
    for (int s = 0; s < KS; ++s) wv[s] *= inv;

    const size_t yb = (size_t)row * D_ + dd;
#pragma unroll
    for (int q = 0; q < 4; ++q) {
        float m[8];
#pragma unroll
        for (int j = 0; j < 8; ++j) m[j] = 0.f;
#pragma unroll
        for (int s = 0; s < KS; ++s) {
            half8 yv = *(const half8*)&ypart[(size_t)s * BN_ * D_ + yb + q * 8];
#pragma unroll
            for (int j = 0; j < 8; ++j) m[j] += wv[s] * (float)yv[j];
        }
        half8 o;
#pragma unroll
        for (int j = 0; j < 8; ++j) o[j] = (half_t)m[j];
        *(half8*)&ymerged[yb + q * 8] = o;
    }
}

// ---- final (MFMA): z = x + ymerged @ Wf ----
// 64x128 tiles, grid (BN/64, 2). Swizzled linear LDS (r3-verified GEMM).
__global__ __launch_bounds__(256) void final_kernel(
    const half_t* __restrict__ ymerged, const float* __restrict__ x,
    const half_t* __restrict__ WfT, float* __restrict__ out)
{
    const int tid = threadIdx.x;
    const int lane = tid & 63;
    const int w = tid >> 6;
    const int lm = lane & 15;
    const int lq = lane >> 4;
    const int r0 = blockIdx.x * 64;
    const int c0 = blockIdx.y * 128;

    __shared__ half_t Ys[64][128];     // y [row][d], swizzled      16,384 B
    __shared__ half_t Wfs[128][128];   // Wf^T [col][d], swizzled   32,768 B

    // stage Wfs: 128 cols x 128 d
    {
        const int wc = tid >> 1, wd = (tid & 1) * 64;
        const half_t* wf = WfT + (size_t)(c0 + wc) * D_ + wd;
#pragma unroll
        for (int q = 0; q < 8; ++q)
            *(half8*)&Wfs[wc][SWZ(wc, wd + q * 8)] = *(const half8*)&wf[q * 8];
    }
    // stage Ys: thread covers row sr, d-range [dd, dd+32)
    {
        const int sr = tid >> 2;
        const int dd = (tid & 3) * 32;
        const half_t* ym = ymerged + (size_t)(r0 + sr) * D_ + dd;
#pragma unroll
        for (int q = 0; q < 4; ++q)
            *(half8*)&Ys[sr][SWZ(sr, dd + q * 8)] = *(const half8*)&ym[q * 8];
    }
    __syncthreads();

    f32x4 acc[8];
#pragma unroll
    for (int nb = 0; nb < 8; ++nb)
#pragma unroll
        for (int r = 0; r < 4; ++r) acc[nb][r] = 0.f;

    const int yrow = w * 16 + lm;
#pragma unroll
    for (int k4 = 0; k4 < 4; ++k4) {
        half8 af = *(const half8*)&Ys[yrow][SWZ(yrow, k4 * 32 + lq * 8)];
#pragma unroll
        for (int nb = 0; nb < 8; ++nb) {
            const int wrow = nb * 16 + lm;
            half8 bf = *(const half8*)&Wfs[wrow][SWZ(wrow, k4 * 32 + lq * 8)];
            acc[nb] = MFMA16x16x32(af, bf, acc[nb]);
        }
    }

#pragma unroll
    for (int nb = 0; nb < 8; ++nb)
#pragma unroll
        for (int r = 0; r < 4; ++r) {
            const int row = r0 + w * 16 + lq * 4 + r;
            const int col = c0 + nb * 16 + lm;
            out[(size_t)row * C_ + col] =
                acc[nb][r] + x[(size_t)row * C_ + col];
        }
}

extern "C" void kernel_launch(void* const* d_in, const int* in_sizes, int n_in,
                              void* d_out, int out_size, void* d_ws, size_t ws_size,
                              hipStream_t stream)
{
    const float* x  = (const float*)d_in[0];
    const float* Wt = (const float*)d_in[1];
    const float* Wp = (const float*)d_in[2];
    const float* Wg = (const float*)d_in[3];
    const float* Wf = (const float*)d_in[4];
    float* out = (float*)d_out;

    const size_t SEG = (size_t)BN_ * D_;   // elements (2,097,152)

    // bytes needed for a given KSPLIT:
    //   (3 proj + KS ypart + 1 ymerged) * SEG halves
    //   + 2 * KS * BN floats (stats) + 4*32768 weight halves
    const size_t need8 = (size_t)(3 + 8 + 1) * SEG * 2
                       + (size_t)2 * 8 * BN_ * 4 + 131072 * 2;
    const int KS = (ws_size >= need8) ? 8 : 4;

    half_t* hb      = (half_t*)d_ws;
    half_t* theta   = hb;
    half_t* pphi    = hb + SEG;
    half_t* pgT     = hb + 2 * SEG;
    half_t* ypart   = hb + 3 * SEG;
    half_t* ymerged = hb + (size_t)(3 + KS) * SEG;
    float*  mstat   = (float*)(hb + (size_t)(3 + KS + 1) * SEG);
    float*  lstat   = mstat + (size_t)KS * BN_;
    half_t* WT_hi   = (half_t*)(lstat + (size_t)KS * BN_);
    half_t* WfT     = WT_hi + 3 * 32768;

    prep_kernel<<<dim3(128, 4), 256, 0, stream>>>(Wt, Wp, Wg, Wf, WT_hi, WfT);
    proj_kernel<<<dim3(BN_ / 64, 3), 256, 0, stream>>>(x, WT_hi, theta, pphi, pgT);
    if (KS == 8) {
        attn_kernel<8><<<dim3(N_ / 128, 8, B_), 256, 0, stream>>>(
            theta, pphi, pgT, ypart, mstat, lstat);
        merge_kernel<8><<<dim3(BN_ * 4 / 256), 256, 0, stream>>>(
            ypart, mstat, lstat, ymerged);
    } else {
        attn_kernel<4><<<dim3(N_ / 128, 4, B_), 256, 0, stream>>>(
            theta, pphi, pgT, ypart, mstat, lstat);
        merge_kernel<4><<<dim3(BN_ * 4 / 256), 256, 0, stream>>>(
            ypart, mstat, lstat, ymerged);
    }
    final_kernel<<<dim3(BN_ / 64, 2), 256, 0, stream>>>(ymerged, x, WfT, out);
}

// Round 6
// 165.198 us; speedup vs baseline: 1.1815x; 1.0590x over previous
//
#include <hip/hip_runtime.h>

#define B_  4
#define N_  4096
#define C_  256
#define D_  128
#define M_  4095
#define BN_ (B_ * N_)

typedef _Float16 half_t;
typedef __attribute__((ext_vector_type(8))) _Float16 half8;
typedef __attribute__((ext_vector_type(4))) _Float16 half4;
typedef __attribute__((ext_vector_type(4))) float f32x4;

#define MFMA16x16x32(A, B, C) __builtin_amdgcn_mfma_f32_16x16x32_f16(A, B, C, 0, 0, 0)
#define LOG2E 1.44269504088896f
#define RTHR  5.0f   // defer-max threshold (base-2): p bounded by 2^5 = 32

// XOR bank swizzle (half-element index) for the final GEMM's linear tiles.
#define SWZ(r, c) ((c) ^ (((r) & 7) << 3))

// ---- prep: weights into B-fragment layouts (runs once, tiny) ----
__global__ __launch_bounds__(256) void prep_kernel(
    const float* __restrict__ Wt, const float* __restrict__ Wp,
    const float* __restrict__ Wg, const float* __restrict__ Wf,
    half_t* __restrict__ WT_hi, half_t* __restrict__ WfT)
{
    const int idx = blockIdx.x * 256 + threadIdx.x;   // 0..32767
    const int wsel = blockIdx.y;
    if (wsel < 3) {
        const float* __restrict__ W = (wsel == 0) ? Wt : (wsel == 1) ? Wp : Wg;
        const int d = idx >> 8, c = idx & 255;
        WT_hi[(size_t)wsel * 32768 + idx] = (half_t)W[(size_t)c * D_ + d];
    } else {
        const int c = idx >> 7, d = idx & 127;
        WfT[idx] = (half_t)Wf[(size_t)d * C_ + c];
    }
}

// ---- proj (single-fp16 MFMA) + FUSED maxpool/transpose ----
// r15: DOUBLE-BUFFERED staging, ONE barrier per K-chunk (was 2). Writes to
// buf^1 overlap MFMA reads of buf; the barrier at loop top is the only sync
// (buf^1's previous readers are separated from this iter's writers by it).
// LDS 30,720 B (pool LsT overlays) -> still 3 blocks/CU.
__global__ __launch_bounds__(256) void proj_kernel(
    const float* __restrict__ x, const half_t* __restrict__ WT_hi,
    half_t* __restrict__ theta, half_t* __restrict__ pphi,
    half_t* __restrict__ pgT)
{
    const int tid = threadIdx.x;
    const int lane = tid & 63;
    const int w = tid >> 6;        // wave -> rows w*16 .. w*16+15
    const int lm = lane & 15;
    const int lq = lane >> 4;
    const int r0 = blockIdx.x * 64;
    const int which = blockIdx.y;
    const half_t* __restrict__ Wg_ = WT_hi + (size_t)which * 32768;

    __shared__ __align__(16) unsigned char lds_raw[30720];
    half_t (*Xh)[64][40]   = (half_t (*)[64][40])(lds_raw);            // 2 x 5,120 B
    half_t (*Whl)[128][40] = (half_t (*)[128][40])(lds_raw + 10240);   // 2 x 10,240 B

    f32x4 acc[8];
#pragma unroll
    for (int nb = 0; nb < 8; ++nb)
#pragma unroll
        for (int r = 0; r < 4; ++r) acc[nb][r] = 0.f;

    const int xr = tid >> 2, xc = (tid & 3) * 8;   // x stage: 64r x 32c
    const int wr = tid >> 1, wc = (tid & 1) * 16;  // W stage: 128d x 32c

    // prefetch chunk 0 into regs, write to buf 0
    const float* xs = x + (size_t)(r0 + xr) * C_ + xc;
    const half_t* wsrc = Wg_ + (size_t)wr * 256 + wc;
    float4 xv0 = *(const float4*)&xs[0];
    float4 xv1 = *(const float4*)&xs[4];
    half8 wv0 = *(const half8*)&wsrc[0];
    half8 wv1 = *(const half8*)&wsrc[8];
    {
        half8 hi;
        hi[0] = (half_t)xv0.x; hi[1] = (half_t)xv0.y;
        hi[2] = (half_t)xv0.z; hi[3] = (half_t)xv0.w;
        hi[4] = (half_t)xv1.x; hi[5] = (half_t)xv1.y;
        hi[6] = (half_t)xv1.z; hi[7] = (half_t)xv1.w;
        *(half8*)&Xh[0][xr][xc] = hi;
        *(half8*)&Whl[0][wr][wc]     = wv0;
        *(half8*)&Whl[0][wr][wc + 8] = wv1;
    }

    int cur = 0;
    for (int kc = 0; kc < 8; ++kc) {   // C = 256 in chunks of 32
        if (kc < 7) {                  // issue next chunk's loads (land under MFMA)
            xs += 32; wsrc += 32;
            xv0 = *(const float4*)&xs[0];
            xv1 = *(const float4*)&xs[4];
            wv0 = *(const half8*)&wsrc[0];
            wv1 = *(const half8*)&wsrc[8];
        }
        __syncthreads();               // buf[cur] writes visible to all waves

        half8 ah = *(const half8*)&Xh[cur][w * 16 + lm][lq * 8];
#pragma unroll
        for (int nb = 0; nb < 8; ++nb) {
            half8 bh = *(const half8*)&Whl[cur][nb * 16 + lm][lq * 8];
            acc[nb] = MFMA16x16x32(ah, bh, acc[nb]);
        }

        if (kc < 7) {                  // write next chunk to the other buffer
            half8 hi;
            hi[0] = (half_t)xv0.x; hi[1] = (half_t)xv0.y;
            hi[2] = (half_t)xv0.z; hi[3] = (half_t)xv0.w;
            hi[4] = (half_t)xv1.x; hi[5] = (half_t)xv1.y;
            hi[6] = (half_t)xv1.z; hi[7] = (half_t)xv1.w;
            *(half8*)&Xh[cur ^ 1][xr][xc] = hi;
            *(half8*)&Whl[cur ^ 1][wr][wc]     = wv0;
            *(half8*)&Whl[cur ^ 1][wr][wc + 8] = wv1;
            cur ^= 1;
        }
    }

    if (which == 0) {   // theta: scale by log2e, store fp16 (QK runs in base-2)
#pragma unroll
        for (int nb = 0; nb < 8; ++nb)
#pragma unroll
            for (int r = 0; r < 4; ++r)
                theta[(size_t)(r0 + w * 16 + lq * 4 + r) * D_ + nb * 16 + lm] =
                    (half_t)(acc[nb][r] * LOG2E);
        return;
    }

    // ---- fused pool path: acc -> LsT[d][m] fp16, halo row, pool, store ----
    __syncthreads();   // staging arrays dead
    half_t (*LsT)[72] = (half_t (*)[72])(lds_raw);   // 128 x 72 = 18,432 B
#pragma unroll
    for (int nb = 0; nb < 8; ++nb) {
        const int d = nb * 16 + lm;
        const int m = w * 16 + lq * 4;
        half4 pk;
#pragma unroll
        for (int r = 0; r < 4; ++r) pk[r] = (half_t)acc[nb][r];
        *(half4*)&LsT[d][m] = pk;
    }
    // halo: projected row r0+64 (or r0+63 at batch boundary) -> LsT[d][64]
    if (tid < 128) {
        int rh = r0 + 64;
        if ((rh & (N_ - 1)) == 0) rh = r0 + 63;
        const float* xrow = x + (size_t)rh * C_;
        const half_t* wrow = Wg_ + (size_t)tid * 256;
        float s = 0.f;
#pragma unroll
        for (int c8 = 0; c8 < 32; ++c8) {
            half8 h = *(const half8*)&wrow[c8 * 8];
            float4 xa = *(const float4*)&xrow[c8 * 8];
            float4 xb = *(const float4*)&xrow[c8 * 8 + 4];
            s += xa.x * (float)h[0] + xa.y * (float)h[1]
               + xa.z * (float)h[2] + xa.w * (float)h[3]
               + xb.x * (float)h[4] + xb.y * (float)h[5]
               + xb.z * (float)h[6] + xb.w * (float)h[7];
        }
        LsT[tid][64] = (half_t)s;
    }
    __syncthreads();

    if (which == 1) {   // pooled phi -> pphi[m][d]
        const int m = tid >> 2, dh = (tid & 3) * 32;
        half8 o[4];
#pragma unroll
        for (int j = 0; j < 32; ++j) {
            float v0 = (float)LsT[dh + j][m];
            float v1 = (float)LsT[dh + j][m + 1];
            o[j >> 3][j & 7] = (half_t)fmaxf(v0, v1);
        }
        half8* dst = (half8*)&pphi[(size_t)(r0 + m) * D_ + dh];
#pragma unroll
        for (int j = 0; j < 4; ++j) dst[j] = o[j];
    } else {            // pooled g -> pgT[b][d][m]
        const int d = tid >> 1, mh = (tid & 1) * 32;
        const int b = r0 / N_, m0 = r0 & (N_ - 1);
        half8 in[4];
#pragma unroll
        for (int j = 0; j < 4; ++j) in[j] = *(const half8*)&LsT[d][mh + j * 8];
        const half_t ext = LsT[d][mh + 32];
        half8 o[4];
#pragma unroll
        for (int j = 0; j < 32; ++j) {
            float v0 = (float)in[j >> 3][j & 7];
            float v1 = (j == 31) ? (float)ext : (float)in[(j + 1) >> 3][(j + 1) & 7];
            o[j >> 3][j & 7] = (half_t)fmaxf(v0, v1);
        }
        half8* dst = (half8*)&pgT[((size_t)b * D_ + d) * N_ + m0 + mh];
#pragma unroll
        for (int j = 0; j < 4; ++j) dst[j] = o[j];
    }
}

// ---------------- MFMA flash attention, transposed scores, base-2 ----------
// FROZEN: r2-measured best (67.4-68.4 us @KS=8). Padded LDS (54,272 B,
// 2 blocks/CU), reg-staged loads between barriers, defer-max, setprio.
template<int KS>
__global__ __launch_bounds__(256, 2) void attn_kernel(
    const half_t* __restrict__ theta, const half_t* __restrict__ pphi,
    const half_t* __restrict__ pgT, half_t* __restrict__ ypart,
    float* __restrict__ mstat, float* __restrict__ lstat)
{
    const int TILES = 64 / KS;     // 64 key-tiles of 64 keys total
    const int tid = threadIdx.x;
    const int lane = tid & 63;
    const int w = tid >> 6;
    const int lm = lane & 15;
    const int lq = lane >> 4;      // 0..3
    const int qt = blockIdx.x, ksb = blockIdx.y, b = blockIdx.z;
    const int q0 = qt * 128;
    const int kt0 = ksb * TILES, kt1 = kt0 + TILES;

    __shared__ half_t Ks[64][136];   // K tile [key][d]        17,408 B
    __shared__ half_t Gts[128][72];  // G tile [d][key]        18,432 B
    __shared__ half_t Ps[128][72];   // P [q][key] wave-private 18,432 B

    // Q B-frags (B[k=d][n=q]): direct fp16 loads (theta already *log2e)
    half8 qh[2][4];
#pragma unroll
    for (int nb = 0; nb < 2; ++nb) {
        const half_t* tr_ = theta + ((size_t)b * N_ + q0 + w * 32 + nb * 16 + lm) * D_;
#pragma unroll
        for (int k4 = 0; k4 < 4; ++k4)
            qh[nb][k4] = *(const half8*)(tr_ + k4 * 32 + lq * 8);
    }

    // hoisted staging addresses (constant per-tile increments)
    const int key = tid >> 2, ch = tid & 3;     // K stage: 64 keys x 128 d
    const int gdd = tid >> 1, gkh = tid & 1;    // G stage: 128 d x 64 keys
    const float4* ksrc = (const float4*)(pphi +
        ((size_t)b * N_ + kt0 * 64 + key) * D_ + ch * 32);
    const float4* gsrc = (const float4*)(pgT +
        ((size_t)b * D_ + gdd) * N_ + kt0 * 64 + gkh * 32);

    float m_i[2] = {-1e30f, -1e30f};
    float l_i[2] = {0.f, 0.f};      // per-quad partial; cross-quad sum deferred
    f32x4 yacc[2][8];
#pragma unroll
    for (int mb = 0; mb < 2; ++mb)
#pragma unroll
        for (int dn = 0; dn < 8; ++dn)
#pragma unroll
            for (int r = 0; r < 4; ++r) yacc[mb][dn][r] = 0.f;

    for (int kt = kt0; kt < kt1; ++kt) {
        const int k0 = kt * 64;
        __syncthreads();
        {   // stage K [key][d] and G^T [d][key] (loads held only briefly)
            float4 a0 = ksrc[0], a1 = ksrc[1], a2 = ksrc[2], a3 = ksrc[3];
            float4 g0 = gsrc[0], g1 = gsrc[1], g2 = gsrc[2], g3 = gsrc[3];
            ksrc += 1024;   // 64 rows * 128 halfs
            gsrc += 8;      // 64 halfs
            float4* kdst = (float4*)&Ks[key][ch * 32];
            kdst[0] = a0; kdst[1] = a1; kdst[2] = a2; kdst[3] = a3;
            float4* gdst = (float4*)&Gts[gdd][gkh * 32];
            gdst[0] = g0; gdst[1] = g1; gdst[2] = g2; gdst[3] = g3;
        }
        __syncthreads();

        // QK^T transposed: S^T[key][q]; A = K (LDS), B = Q (regs)
        f32x4 sc[4][2];
#pragma unroll
        for (int kb = 0; kb < 4; ++kb)
#pragma unroll
            for (int nb = 0; nb < 2; ++nb)
#pragma unroll
                for (int r = 0; r < 4; ++r) sc[kb][nb][r] = 0.f;
        __builtin_amdgcn_s_setprio(1);
#pragma unroll
        for (int kb = 0; kb < 4; ++kb) {
#pragma unroll
            for (int k4 = 0; k4 < 4; ++k4) {
                half8 kf = *(const half8*)&Ks[kb * 16 + lm][k4 * 32 + lq * 8];
#pragma unroll
                for (int nb = 0; nb < 2; ++nb)
                    sc[kb][nb] = MFMA16x16x32(kf, qh[nb][k4], sc[kb][nb]);
            }
        }
        __builtin_amdgcn_s_setprio(0);
        // mask padded key 4095 (only last tile of last split)
        if (k0 + 64 > M_) {
#pragma unroll
            for (int kb = 0; kb < 4; ++kb)
#pragma unroll
                for (int r = 0; r < 4; ++r)
                    if (k0 + kb * 16 + lq * 4 + r >= M_) {
                        sc[kb][0][r] = -1e30f; sc[kb][1][r] = -1e30f;
                    }
        }

        // ---- online softmax (base-2) with defer-max ----
        float mt[2];
#pragma unroll
        for (int nb = 0; nb < 2; ++nb) {
            float m0 = -1e30f;
#pragma unroll
            for (int kb = 0; kb < 4; ++kb)
#pragma unroll
                for (int r = 0; r < 4; ++r) m0 = fmaxf(m0, sc[kb][nb][r]);
            m0 = fmaxf(m0, __shfl_xor(m0, 16, 64));
            m0 = fmaxf(m0, __shfl_xor(m0, 32, 64));
            mt[nb] = m0;   // uniform across quads, per q-col lm
        }
        const bool need0 = __any(mt[0] > m_i[0] + RTHR);
        const bool need1 = __any(mt[1] > m_i[1] + RTHR);
        float alphav[2] = {1.f, 1.f};
#pragma unroll
        for (int nb = 0; nb < 2; ++nb) {
            const bool need = nb ? need1 : need0;
            float mnew = m_i[nb];
            if (need) {   // wave-uniform (rare after first tiles)
                mnew = fmaxf(m_i[nb], mt[nb]);
                alphav[nb] = exp2f(m_i[nb] - mnew);
                m_i[nb] = mnew;
            }
            float rs = 0.f;
#pragma unroll
            for (int kb = 0; kb < 4; ++kb) {
                half4 pk;
#pragma unroll
                for (int r = 0; r < 4; ++r) {
                    float p = exp2f(sc[kb][nb][r] - mnew);   // p <= 2^RTHR
                    rs += p;
                    pk[r] = (half_t)p;
                }
                *(half4*)&Ps[w * 32 + nb * 16 + lm][kb * 16 + lq * 4] = pk;
            }
            l_i[nb] = l_i[nb] * alphav[nb] + rs;
        }
        // rescale accumulator only on rescue tiles (wave-uniform branches)
        if (need0) {
            float a_t[4];
#pragma unroll
            for (int r = 0; r < 4; ++r) a_t[r] = __shfl(alphav[0], lq * 4 + r, 16);
#pragma unroll
            for (int dn = 0; dn < 8; ++dn)
#pragma unroll
                for (int r = 0; r < 4; ++r) yacc[0][dn][r] *= a_t[r];
        }
        if (need1) {
            float a_t[4];
#pragma unroll
            for (int r = 0; r < 4; ++r) a_t[r] = __shfl(alphav[1], lq * 4 + r, 16);
#pragma unroll
            for (int dn = 0; dn < 8; ++dn)
#pragma unroll
                for (int r = 0; r < 4; ++r) yacc[1][dn][r] *= a_t[r];
        }

        // PV: A = P (LDS, wave-private -> no barrier), B = G^T (LDS)
        half8 pf[2][2];
#pragma unroll
        for (int mb = 0; mb < 2; ++mb)
#pragma unroll
            for (int k2 = 0; k2 < 2; ++k2)
                pf[mb][k2] = *(const half8*)&Ps[w * 32 + mb * 16 + lm][k2 * 32 + lq * 8];
        __builtin_amdgcn_s_setprio(1);
#pragma unroll
        for (int dn = 0; dn < 8; ++dn) {
#pragma unroll
            for (int k2 = 0; k2 < 2; ++k2) {
                half8 gf = *(const half8*)&Gts[dn * 16 + lm][k2 * 32 + lq * 8];
                yacc[0][dn] = MFMA16x16x32(pf[0][k2], gf, yacc[0][dn]);
                yacc[1][dn] = MFMA16x16x32(pf[1][k2], gf, yacc[1][dn]);
            }
        }
        __builtin_amdgcn_s_setprio(0);
    }

    // epilogue: finish l (cross-quad sum, deferred from the k-loop)
#pragma unroll
    for (int nb = 0; nb < 2; ++nb) {
        l_i[nb] += __shfl_xor(l_i[nb], 16, 64);
        l_i[nb] += __shfl_xor(l_i[nb], 32, 64);
    }
    // unnormalized y partial (fp16) + (m,l) stats (m in base-2)
    half_t* yp = ypart + ((size_t)ksb * BN_ + (size_t)b * N_) * D_;
#pragma unroll
    for (int mb = 0; mb < 2; ++mb)
#pragma unroll
        for (int dn = 0; dn < 8; ++dn)
#pragma unroll
            for (int r = 0; r < 4; ++r)
                yp[(size_t)(q0 + w * 32 + mb * 16 + lq * 4 + r) * D_ + dn * 16 + lm] =
                    (half_t)yacc[mb][dn][r];
    if (lq == 0) {
#pragma unroll
        for (int nb = 0; nb < 2; ++nb) {
            const int row = q0 + w * 32 + nb * 16 + lm;
            mstat[(size_t)ksb * BN_ + (size_t)b * N_ + row] = m_i[nb];
            lstat[(size_t)ksb * BN_ + (size_t)b * N_ + row] = l_i[nb];
        }
    }
}

// ---- merge: KS ypart partials -> ymerged (fp16), once per row ----
// r15: grid 256 -> 1024 blocks (half8 per thread, 4 blocks/CU; was 1/CU).
template<int KS>
__global__ __launch_bounds__(256) void merge_kernel(
    const half_t* __restrict__ ypart, const float* __restrict__ mstat,
    const float* __restrict__ lstat, half_t* __restrict__ ymerged)
{
    const int idx = blockIdx.x * 256 + threadIdx.x;   // 0 .. BN_*16-1
    const int row = idx >> 4;
    const int c8 = (idx & 15) * 8;

    float mv[KS], lv[KS], wv[KS];
    float Mx = -1e30f;
#pragma unroll
    for (int s = 0; s < KS; ++s) {
        mv[s] = mstat[(size_t)s * BN_ + row];
        lv[s] = lstat[(size_t)s * BN_ + row];
        Mx = fmaxf(Mx, mv[s]);
    }
    float lsum = 0.f;
#pragma unroll
    for (int s = 0; s < KS; ++s) { wv[s] = exp2f(mv[s] - Mx); lsum += wv[s] * lv[s]; }
    const float inv = 1.f / lsum;
#pragma unroll
    for (int s = 0; s < KS; ++s) wv[s] *= inv;

    const size_t yb = (size_t)row * D_ + c8;
    float m[8];
#pragma unroll
    for (int j = 0; j < 8; ++j) m[j] = 0.f;
#pragma unroll
    for (int s = 0; s < KS; ++s) {
        half8 yv = *(const half8*)&ypart[(size_t)s * BN_ * D_ + yb];
#pragma unroll
        for (int j = 0; j < 8; ++j) m[j] += wv[s] * (float)yv[j];
    }
    half8 o;
#pragma unroll
    for (int j = 0; j < 8; ++j) o[j] = (half_t)m[j];
    *(half8*)&ymerged[yb] = o;
}

// ---- final (MFMA): z = x + ymerged @ Wf ---- (unchanged from r5)
__global__ __launch_bounds__(256) void final_kernel(
    const half_t* __restrict__ ymerged, const float* __restrict__ x,
    const half_t* __restrict__ WfT, float* __restrict__ out)
{
    const int tid = threadIdx.x;
    const int lane = tid & 63;
    const int w = tid >> 6;
    const int lm = lane & 15;
    const int lq = lane >> 4;
    const int r0 = blockIdx.x * 64;
    const int c0 = blockIdx.y * 128;

    __shared__ half_t Ys[64][128];     // y [row][d], swizzled      16,384 B
    __shared__ half_t Wfs[128][128];   // Wf^T [col][d], swizzled   32,768 B

    // stage Wfs: 128 cols x 128 d
    {
        const int wc = tid >> 1, wd = (tid & 1) * 64;
        const half_t* wf = WfT + (size_t)(c0 + wc) * D_ + wd;
#pragma unroll
        for (int q = 0; q < 8; ++q)
            *(half8*)&Wfs[wc][SWZ(wc, wd + q * 8)] = *(const half8*)&wf[q * 8];
    }
    // stage Ys: thread covers row sr, d-range [dd, dd+32)
    {
        const int sr = tid >> 2;
        const int dd = (tid & 3) * 32;
        const half_t* ym = ymerged + (size_t)(r0 + sr) * D_ + dd;
#pragma unroll
        for (int q = 0; q < 4; ++q)
            *(half8*)&Ys[sr][SWZ(sr, dd + q * 8)] = *(const half8*)&ym[q * 8];
    }
    __syncthreads();

    f32x4 acc[8];
#pragma unroll
    for (int nb = 0; nb < 8; ++nb)
#pragma unroll
        for (int r = 0; r < 4; ++r) acc[nb][r] = 0.f;

    const int yrow = w * 16 + lm;
#pragma unroll
    for (int k4 = 0; k4 < 4; ++k4) {
        half8 af = *(const half8*)&Ys[yrow][SWZ(yrow, k4 * 32 + lq * 8)];
#pragma unroll
        for (int nb = 0; nb < 8; ++nb) {
            const int wrow = nb * 16 + lm;
            half8 bf = *(const half8*)&Wfs[wrow][SWZ(wrow, k4 * 32 + lq * 8)];
            acc[nb] = MFMA16x16x32(af, bf, acc[nb]);
        }
    }

#pragma unroll
    for (int nb = 0; nb < 8; ++nb)
#pragma unroll
        for (int r = 0; r < 4; ++r) {
            const int row = r0 + w * 16 + lq * 4 + r;
            const int col = c0 + nb * 16 + lm;
            out[(size_t)row * C_ + col] =
                acc[nb][r] + x[(size_t)row * C_ + col];
        }
}

extern "C" void kernel_launch(void* const* d_in, const int* in_sizes, int n_in,
                              void* d_out, int out_size, void* d_ws, size_t ws_size,
                              hipStream_t stream)
{
    const float* x  = (const float*)d_in[0];
    const float* Wt = (const float*)d_in[1];
    const float* Wp = (const float*)d_in[2];
    const float* Wg = (const float*)d_in[3];
    const float* Wf = (const float*)d_in[4];
    float* out = (float*)d_out;

    const size_t SEG = (size_t)BN_ * D_;   // elements (2,097,152)

    // bytes needed for a given KSPLIT:
    //   (3 proj + KS ypart + 1 ymerged) * SEG halves
    //   + 2 * KS * BN floats (stats) + 4*32768 weight halves
    const size_t need8 = (size_t)(3 + 8 + 1) * SEG * 2
                       + (size_t)2 * 8 * BN_ * 4 + 131072 * 2;
    const int KS = (ws_size >= need8) ? 8 : 4;

    half_t* hb      = (half_t*)d_ws;
    half_t* theta   = hb;
    half_t* pphi    = hb + SEG;
    half_t* pgT     = hb + 2 * SEG;
    half_t* ypart   = hb + 3 * SEG;
    half_t* ymerged = hb + (size_t)(3 + KS) * SEG;
    float*  mstat   = (float*)(hb + (size_t)(3 + KS + 1) * SEG);
    float*  lstat   = mstat + (size_t)KS * BN_;
    half_t* WT_hi   = (half_t*)(lstat + (size_t)KS * BN_);
    half_t* WfT     = WT_hi + 3 * 32768;

    prep_kernel<<<dim3(128, 4), 256, 0, stream>>>(Wt, Wp, Wg, Wf, WT_hi, WfT);
    proj_kernel<<<dim3(BN_ / 64, 3), 256, 0, stream>>>(x, WT_hi, theta, pphi, pgT);
    if (KS == 8) {
        attn_kernel<8><<<dim3(N_ / 128, 8, B_), 256, 0, stream>>>(
            theta, pphi, pgT, ypart, mstat, lstat);
        merge_kernel<8><<<dim3(BN_ * 16 / 256), 256, 0, stream>>>(
            ypart, mstat, lstat, ymerged);
    } else {
        attn_kernel<4><<<dim3(N_ / 128, 4, B_), 256, 0, stream>>>(
            theta, pphi, pgT, ypart, mstat, lstat);
        merge_kernel<4><<<dim3(BN_ * 16 / 256), 256, 0, stream>>>(
            ypart, mstat, lstat, ymerged);
    }
    final_kernel<<<dim3(BN_ / 64, 2), 256, 0, stream>>>(ymerged, x, WfT, out);
}